// Round 1
// baseline (80.598 us; speedup 1.0000x reference)
//
#include <hip/hip_runtime.h>
#include <math.h>

#define EPS_NORM 1e-8f
#define EPS_ERR  1e-8f

__device__ inline void norm3(float& x, float& y, float& z) {
    float nn = sqrtf(x*x + y*y + z*z);
    float inv = 1.0f / fmaxf(nn, EPS_NORM);
    x *= inv; y *= inv; z *= inv;
}

// F layout: frames[b,n,3(row d = xyz),3(col k = point a/b/c)], flat base = (bi*n+j)*9
// a[d] = F[base + d*3 + 0], bpt[d] = F[base + d*3 + 1], c[d] = F[base + d*3 + 2]
__device__ inline void basis_from_frame(const float* __restrict__ F, size_t base,
                                        float* e /*[9]: e1,e2,e3 xyz*/, float* o /*[3]*/) {
    float ax = F[base + 0], bx = F[base + 1], cx = F[base + 2];
    float ay = F[base + 3], by = F[base + 4], cy = F[base + 5];
    float az = F[base + 6], bz = F[base + 7], cz = F[base + 8];
    float w1x = ax - bx, w1y = ay - by, w1z = az - bz;
    float w2x = cx - bx, w2y = cy - by, w2z = cz - bz;
    norm3(w1x, w1y, w1z);
    norm3(w2x, w2y, w2z);
    float e1x = w1x + w2x, e1y = w1y + w2y, e1z = w1z + w2z;
    float e2x = w2x - w1x, e2y = w2y - w1y, e2z = w2z - w1z;
    norm3(e1x, e1y, e1z);
    norm3(e2x, e2y, e2z);
    float e3x = e1y * e2z - e1z * e2y;
    float e3y = e1z * e2x - e1x * e2z;
    float e3z = e1x * e2y - e1y * e2x;
    e[0] = e1x; e[1] = e1y; e[2] = e1z;
    e[3] = e2x; e[4] = e2y; e[5] = e2z;
    e[6] = e3x; e[7] = e3y; e[8] = e3z;
    // projected origin: o[k] = dot(bpt, e_k)
    o[0] = bx * e1x + by * e1y + bz * e1z;
    o[1] = bx * e2x + by * e2y + bz * e2z;
    o[2] = bx * e3x + by * e3y + bz * e3z;
}

// One thread per (b,j) frame pair; writes 24 floats: ep[9], op[3], et[9], ot[3]
__global__ __launch_bounds__(256) void frames_kernel(
    const float* __restrict__ predF, const float* __restrict__ trueF,
    float* __restrict__ fd, int total_bn)
{
    int idx = blockIdx.x * 256 + threadIdx.x;
    if (idx >= total_bn) return;
    float e[9], o[3];
    float* dst = fd + (size_t)idx * 24;
    basis_from_frame(predF, (size_t)idx * 9, e, o);
    #pragma unroll
    for (int k = 0; k < 9; ++k) dst[k] = e[k];
    #pragma unroll
    for (int k = 0; k < 3; ++k) dst[9 + k] = o[k];
    basis_from_frame(trueF, (size_t)idx * 9, e, o);
    #pragma unroll
    for (int k = 0; k < 9; ++k) dst[12 + k] = e[k];
    #pragma unroll
    for (int k = 0; k < 3; ++k) dst[21 + k] = o[k];
}

// Each thread: one j (coalesced out-writes), IT consecutive i's (amortize frame load)
template<int IT>
__global__ __launch_bounds__(256) void pair_err_kernel(
    const float* __restrict__ cp, const float* __restrict__ ct,
    const float* __restrict__ fd, float* __restrict__ out, int n)
{
    int j  = blockIdx.x * 256 + threadIdx.x;
    int bi = blockIdx.z;
    if (j >= n) return;

    const float4* f4 = reinterpret_cast<const float4*>(fd + ((size_t)bi * n + j) * 24);
    float4 q0 = f4[0], q1 = f4[1], q2 = f4[2], q3 = f4[3], q4 = f4[4], q5 = f4[5];
    const float ep0 = q0.x, ep1 = q0.y, ep2 = q0.z,
                ep3 = q0.w, ep4 = q1.x, ep5 = q1.y,
                ep6 = q1.z, ep7 = q1.w, ep8 = q2.x;
    const float op0 = q2.y, op1 = q2.z, op2 = q2.w;
    const float et0 = q3.x, et1 = q3.y, et2 = q3.z,
                et3 = q3.w, et4 = q4.x, et5 = q4.y,
                et6 = q4.z, et7 = q4.w, et8 = q5.x;
    const float ot0 = q5.y, ot1 = q5.z, ot2 = q5.w;

    const int i0 = blockIdx.y * IT;
    #pragma unroll
    for (int ii = 0; ii < IT; ++ii) {
        int i = i0 + ii;
        if (i >= n) break;
        size_t cbase = ((size_t)bi * n + i) * 3;
        float px = cp[cbase + 0], py = cp[cbase + 1], pz = cp[cbase + 2];
        float tx = ct[cbase + 0], ty = ct[cbase + 1], tz = ct[cbase + 2];
        float d0 = (px * ep0 + py * ep1 + pz * ep2 - op0) - (tx * et0 + ty * et1 + tz * et2 - ot0);
        float d1 = (px * ep3 + py * ep4 + pz * ep5 - op1) - (tx * et3 + ty * et4 + tz * et5 - ot1);
        float d2 = (px * ep6 + py * ep7 + pz * ep8 - op2) - (tx * et6 + ty * et7 + tz * et8 - ot2);
        out[((size_t)bi * n + i) * n + j] = sqrtf(d0 * d0 + d1 * d1 + d2 * d2 + EPS_ERR);
    }
}

extern "C" void kernel_launch(void* const* d_in, const int* in_sizes, int n_in,
                              void* d_out, int out_size, void* d_ws, size_t ws_size,
                              hipStream_t stream) {
    const float* pred_coords = (const float*)d_in[0];
    const float* true_coords = (const float*)d_in[1];
    const float* pred_frames = (const float*)d_in[2];
    const float* true_frames = (const float*)d_in[3];
    float* out = (float*)d_out;

    // in_sizes[0] = b*n*3 ; out_size = b*n*n  ->  n = out_size / (b*n), b = bn/n
    int total_bn = in_sizes[0] / 3;
    int n = (int)((long long)out_size / total_bn);
    int b = total_bn / n;

    float* fd = (float*)d_ws;  // total_bn * 24 floats (96 B per frame pair)

    int blocks1 = (total_bn + 255) / 256;
    frames_kernel<<<blocks1, 256, 0, stream>>>(pred_frames, true_frames, fd, total_bn);

    constexpr int IT = 8;
    dim3 grid((n + 255) / 256, (n + IT - 1) / IT, b);
    pair_err_kernel<IT><<<grid, 256, 0, stream>>>(pred_coords, true_coords, fd, out, n);
}